// Round 8
// baseline (117.239 us; speedup 1.0000x reference)
//
#include <hip/hip_runtime.h>

// out[b,n,f] = lo[f]*x[b,n,f-1] + hi[f]*x[b,n,f+1]
// lo[f] = adj_t[f, f-1] (f>=1 else 0), hi[f] = adj_t[f, f+1] (f<=T-2 else 0)
// B=64, N=512, T=512. Memory-bound band stencil: 134 MB traffic -> ~21 us roofline.

#define T_DIM 512

// Extract the two off-diagonals of adj_t into ws: ws[0..T) = lo, ws[T..2T) = hi.
// lo[0] = 0 and hi[T-1] = 0 make cross-row shuffle leakage harmless.
__global__ void coef_prep(const float* __restrict__ adj, float* __restrict__ ws) {
    int f = blockIdx.x * blockDim.x + threadIdx.x;
    if (f < T_DIM) {
        ws[f]         = (f >= 1)        ? adj[(size_t)f * T_DIM + (f - 1)] : 0.0f;
        ws[T_DIM + f] = (f < T_DIM - 1) ? adj[(size_t)f * T_DIM + (f + 1)] : 0.0f;
    }
}

// One float4 per thread per grid-stride iteration. Neighbor elements come from
// adjacent lanes via shuffle (a wave covers 1 KiB contiguous); only the two
// wave-edge lanes do a (exec-masked) scalar load. 1 vector load + 1 vector
// store per 16B of output -> pure-copy memory pattern.
__global__ __launch_bounds__(256) void band_stencil(
        const float* __restrict__ x,
        const float* __restrict__ ws,
        float* __restrict__ out,
        long total_vec /* B*N*T/4 */) {
    const int lane = threadIdx.x & 63;
    const long stride = (long)gridDim.x * blockDim.x;
    const long total_elems = total_vec * 4;

    const float4* __restrict__ x4  = (const float4*)x;
    const float4* __restrict__ lo4 = (const float4*)ws;
    const float4* __restrict__ hi4 = (const float4*)(ws + T_DIM);
    float4* __restrict__ o4 = (float4*)out;

    for (long v = (long)blockIdx.x * blockDim.x + threadIdx.x; v < total_vec; v += stride) {
        float4 xv = x4[v];
        int f4 = (int)(v & (T_DIM / 4 - 1));   // vec index within the T-row
        float4 lo = lo4[f4];                   // 4 KB table, L1-resident
        float4 hi = hi4[f4];

        // neighbors from adjacent lanes (lanes hold consecutive vecs)
        float xm1 = __shfl_up(xv.w, 1);        // lane-1's last element  = x[g-1]
        float xp4 = __shfl_down(xv.x, 1);      // lane+1's first element = x[g+4]

        long g = v * 4;
        if (lane == 0)
            xm1 = (g > 0) ? x[g - 1] : 0.0f;
        if (lane == 63 || v == total_vec - 1)
            xp4 = (g + 4 < total_elems) ? x[g + 4] : 0.0f;

        // Cross-row leakage at f=0 / f=T-1 is multiplied by lo[0]=0 / hi[T-1]=0.
        float4 o;
        o.x = lo.x * xm1  + hi.x * xv.y;
        o.y = lo.y * xv.x + hi.y * xv.z;
        o.z = lo.z * xv.y + hi.z * xv.w;
        o.w = lo.w * xv.z + hi.w * xp4;
        o4[v] = o;
    }
}

extern "C" void kernel_launch(void* const* d_in, const int* in_sizes, int n_in,
                              void* d_out, int out_size, void* d_ws, size_t ws_size,
                              hipStream_t stream) {
    const float* x   = (const float*)d_in[0];   // [B, N, T] fp32
    const float* adj = (const float*)d_in[1];   // [T, T] fp32
    float* out = (float*)d_out;                 // [B, N, T] fp32
    float* ws  = (float*)d_ws;                  // >= 2*T floats

    // 1) extract band coefficients (ws is re-poisoned every call, so always run)
    coef_prep<<<(T_DIM + 255) / 256, 256, 0, stream>>>(adj, ws);

    // 2) streaming band stencil: ~2048 blocks, grid-stride (G11: 8 blocks/CU,
    //    32 waves/CU occupancy), each thread does 8 full-wave iterations.
    long total_vec = (long)out_size / 4;        // 4,194,304
    int nblocks = (int)((total_vec + 255) / 256);
    if (nblocks > 2048) nblocks = 2048;
    band_stencil<<<nblocks, 256, 0, stream>>>(x, ws, out, total_vec);
}